// Round 14
// baseline (41.131 us; speedup 1.0000x reference)
//
#include <hip/hip_runtime.h>
#include <hip/hip_fp16.h>
#include <float.h>

constexpr int KMAX  = 11;    // KS_MAX
constexpr int SEQ   = 512;   // SEQ_LEN
constexpr int NB    = 64;    // BATCH
constexpr int NBB   = 8;     // batches per main block (8 groups)
constexpr int NGRP  = NB / NBB;
constexpr int KPB   = 4;     // kernels per block = 1 per wave
constexpr int MSTR  = 32;    // meta ints per k: [0]=nj [1..11]=c [12..22]=w2bits
constexpr int SBASE = 512;   // fixed window: slot = s + 512
constexpr int WSLOT = 1600;  // s in [-512, 1088). Bound proof: pad>0 => c<=2 and
                             // lout<=1022 => s_max = lout+62+2 = 1086; pad=0 =>
                             // lout+c_max = 512 => s_max = 574. s_min = -2*pad >= -510.
constexpr int NPAD  = NGRP * (WSLOT - SEQ);   // 8704 zero slots in xtg
constexpr int ZBLK  = (NPAD + 255) / 256;     // 34 zero-fill blocks

__device__ __forceinline__ unsigned h2b(__half2 h) { unsigned u; __builtin_memcpy(&u, &h, 4); return u; }
__device__ __forceinline__ __half2  b2h(unsigned u) { __half2 h; __builtin_memcpy(&h, &u, 4); return h; }

// ROCm 7.2 has no __hmax2/__hmin2 — use VOP3P directly.
__device__ __forceinline__ unsigned pkmax(unsigned a, unsigned b) {
    unsigned d; asm("v_pk_max_f16 %0, %1, %2" : "=v"(d) : "v"(a), "v"(b)); return d;
}
__device__ __forceinline__ unsigned pkadd(unsigned a, unsigned b) { return h2b(__hadd2(b2h(a), b2h(b))); }
__device__ __forceinline__ __half2 h2max(__half2 a, __half2 b) { return b2h(pkmax(h2b(a), h2b(b))); }
// fused (a*b+c) clamped to [0,1] — the whole count update in one VOP3P
__device__ __forceinline__ unsigned pkfma_clamp(unsigned a, unsigned b, unsigned c) {
    unsigned d; asm("v_pk_fma_f16 %0, %1, %2, %3 clamp" : "=v"(d) : "v"(a), "v"(b), "v"(c)); return d;
}

template<int CTRL>
__device__ __forceinline__ unsigned dppmov(unsigned old, unsigned v) {
    return (unsigned)__builtin_amdgcn_update_dpp((int)old, (int)v, CTRL, 0xF, 0xF, false);
}
constexpr unsigned NEGINF2 = 0xFC00FC00u;   // -inf | -inf (f16 pair)

__device__ __forceinline__ unsigned dpp_redmax(unsigned x) {
    x = pkmax(x, dppmov<0xB1 >(NEGINF2, x));  // quad_perm xor1
    x = pkmax(x, dppmov<0x4E >(NEGINF2, x));  // quad_perm xor2
    x = pkmax(x, dppmov<0x141>(NEGINF2, x));  // row_half_mirror
    x = pkmax(x, dppmov<0x140>(NEGINF2, x));  // row_mirror
    x = pkmax(x, dppmov<0x142>(NEGINF2, x));  // row_bcast15
    x = pkmax(x, dppmov<0x143>(NEGINF2, x));  // row_bcast31
    return x;                                  // lane 63 valid
}
__device__ __forceinline__ unsigned dpp_redadd(unsigned x) {
    x = pkadd(x, dppmov<0xB1 >(0u, x));
    x = pkadd(x, dppmov<0x4E >(0u, x));
    x = pkadd(x, dppmov<0x141>(0u, x));
    x = pkadd(x, dppmov<0x140>(0u, x));
    x = pkadd(x, dppmov<0x142>(0u, x));
    x = pkadd(x, dppmov<0x143>(0u, x));
    return x;                                  // lane 63 valid
}

// ======================= prep kernel =======================
// blocks [0, K):          meta: c_kj via ONE stride-16 probe + compaction.
// blocks [K, K+32):       transpose+convert x -> xtg[g][SBASE+s][8] f16
// blocks [K+32, K+32+34): zero xtg pad slots ([0,512) and [1024,1600) per grp)
__global__ __launch_bounds__(256)
void prep_kernel(const float* __restrict__ x, const float* __restrict__ w,
                 const int* __restrict__ idx, int* __restrict__ meta,
                 unsigned short* __restrict__ xtg, int K, int maxL)
{
    const int tid = threadIdx.x;
    const int blk = blockIdx.x;
    if (blk >= K + 32) {                         // ---- zero pads ----
        const int p = (blk - K - 32) * 256 + tid;
        if (p < NPAD) {
            const int g = p / (WSLOT - SEQ);
            const int r = p - g * (WSLOT - SEQ);
            const int slot = (r < SBASE) ? r : r + SEQ;   // [0,512) U [1024,1600)
            *reinterpret_cast<float4*>(xtg + ((size_t)g * WSLOT + slot) * NBB) =
                make_float4(0.f, 0.f, 0.f, 0.f);
        }
        return;
    }
    if (blk >= K) {                              // ---- transpose ----
        const int j  = (blk - K) * 256 + tid;    // 0..8191
        const int b  = j >> 7, s4 = j & 127;
        const float4 v = reinterpret_cast<const float4*>(x)[b * (SEQ / 4) + s4];
        const int g = b >> 3, bl = b & 7;
        unsigned short* dst = xtg + ((size_t)g * WSLOT + SBASE + s4 * 4) * NBB + bl;
        __half h;
        h = __float2half_rn(v.x); __builtin_memcpy(&dst[0 * NBB], &h, 2);
        h = __float2half_rn(v.y); __builtin_memcpy(&dst[1 * NBB], &h, 2);
        h = __float2half_rn(v.z); __builtin_memcpy(&dst[2 * NBB], &h, 2);
        h = __float2half_rn(v.w); __builtin_memcpy(&dst[3 * NBB], &h, 2);
        return;
    }

    // ---- meta: idx[k,j,t] = clip(t+c, 0, 511); interior value (0<v<511) => c = v-t.
    // Stride-16 probe t = 0,16,...,1008: the interior t-run has width >= 510 when it
    // starts at t<=510 (pad taps: start = 2p-jd <= 510), and taps with jd-2p > 0 are
    // interior at t=0. Either way {0,16,...,1008} intersects the run. Fallback kept.
    __shared__ int c_sh[KMAX];
    const int k = blk, wave = tid >> 6, lane = tid & 63;
    const int tprobe = min(lane * 16, maxL - 1);

    int vv[3] = {0, 0, 0};
#pragma unroll
    for (int i = 0; i < 3; ++i) {                // hoist: all probe loads in flight
        const int j = wave + i * 4;
        if (j < KMAX) vv[i] = idx[((size_t)k * KMAX + j) * (size_t)maxL + tprobe];
    }
#pragma unroll
    for (int i = 0; i < 3; ++i) {
        const int j = wave + i * 4;              // wave-uniform guard
        if (j < KMAX) {
            int c = 0;                           // fallback c=0 (in-window, w=0 -> 0)
            const bool interior = (vv[i] > 0) && (vv[i] < SEQ - 1);
            const unsigned long long mb = __ballot(interior);
            if (mb != 0ull) {
                const int fl = __builtin_ctzll(mb);
                c = __shfl(vv[i], fl) - min(fl * 16, maxL - 1);
            } else {
                const int* row = idx + ((size_t)k * KMAX + j) * (size_t)maxL;
                for (int base = 0; base < maxL; base += 64) {
                    const int t2 = base + lane;
                    const int v2 = (t2 < maxL) ? row[t2] : 0;
                    const bool in2 = (v2 > 0) && (v2 < SEQ - 1);
                    const unsigned long long mb2 = __ballot(in2);
                    if (mb2 != 0ull) {
                        const int fl2 = __builtin_ctzll(mb2);
                        c = __shfl(v2, fl2) - (base + fl2);
                        break;
                    }
                }
            }
            if (lane == 0) c_sh[j] = c;
        }
    }
    __syncthreads();

    if (tid == 0) {
        int* mk = meta + (size_t)k * MSTR;
        int n = 0;
        for (int j = 0; j < KMAX; ++j) {
            const float wj = w[(size_t)k * KMAX + j];
            if (wj != 0.0f) {
                mk[1 + n] = c_sh[j];
                __half hw = __float2half_rn(wj);
                unsigned short ub; __builtin_memcpy(&ub, &hw, 2);
                mk[12 + n] = (unsigned)ub | ((unsigned)ub << 16);
                ++n;
            }
        }
        for (int jj = n; jj < KMAX; ++jj) { mk[1 + jj] = 0; mk[12 + jj] = 0; }   // in-window, w=0
        mk[0] = n;
    }
}

// ======================= main kernel =======================
// grid (K/4, 8). Fixed window staged once in LDS; ONE barrier; wave owns k.
// DUAL-PIPE conv: even taps read the LDS window (ds_read_b128), odd taps read
// the IDENTICAL window from global xtg (global_load_dwordx4, L1/L2-resident,
// separate pipe from DS) — same slot arithmetic for both. Zero fringes in both
// copies make every read in-window and out-of-range taps contribute exactly 0.
template<int NJ>
__device__ __forceinline__ void conv_wave(
    const char* __restrict__ xsc, const char* __restrict__ gxt,
    int mrow, int lout, int lane, unsigned ctermb,
    unsigned (&um)[4], unsigned (&uc)[4])
{
    const __half2 zero2 = __float2half2_rn(0.f);
    const __half2 nbig2 = __float2half2_rn(-65504.f);
    const unsigned C4b  = 0x74007400u;   // f16 pair {2^14, 2^14}

    int addr[NJ]; __half2 wr[NJ];
#pragma unroll
    for (int j = 0; j < NJ; ++j) {
        const int c = __builtin_amdgcn_readlane(mrow, 1 + j);
        wr[j]   = b2h((unsigned)__builtin_amdgcn_readlane(mrow, 12 + j));
        addr[j] = (lane + c + SBASE) * 16;
    }
    __half2 mx2[4], ct2[4];
#pragma unroll
    for (int m = 0; m < 4; ++m) { mx2[m] = nbig2; ct2[m] = zero2; }

    const int nfull = lout >> 6;
    const int ng4   = nfull >> 2;

    for (int g = 0; g < ng4; ++g) {       // groups of 4 full chunks, immediate offsets
#pragma unroll
        for (int u = 0; u < 4; ++u) {
            uint4 d[NJ];
#pragma unroll
            for (int j = 0; j < NJ; ++j) {
                if (j & 1) d[j] = *reinterpret_cast<const uint4*>(gxt + addr[j] + u * 1024);
                else       d[j] = *reinterpret_cast<const uint4*>(xsc + addr[j] + u * 1024);
            }
            __half2 a[4] = {zero2, zero2, zero2, zero2};
#pragma unroll
            for (int j = 0; j < NJ; ++j) {
                a[0] = __hfma2(wr[j], b2h(d[j].x), a[0]);
                a[1] = __hfma2(wr[j], b2h(d[j].y), a[1]);
                a[2] = __hfma2(wr[j], b2h(d[j].z), a[2]);
                a[3] = __hfma2(wr[j], b2h(d[j].w), a[3]);
            }
#pragma unroll
            for (int m = 0; m < 4; ++m) {
                mx2[m] = h2max(mx2[m], a[m]);
                ct2[m] = b2h(pkadd(h2b(ct2[m]), pkfma_clamp(h2b(a[m]), C4b, ctermb)));
            }
        }
#pragma unroll
        for (int j = 0; j < NJ; ++j) addr[j] += 4096;
    }
    for (int u = 0; u < (nfull & 3); ++u) {   // leftover full chunks
        uint4 d[NJ];
#pragma unroll
        for (int j = 0; j < NJ; ++j) {
            if (j & 1) d[j] = *reinterpret_cast<const uint4*>(gxt + addr[j]);
            else       d[j] = *reinterpret_cast<const uint4*>(xsc + addr[j]);
        }
        __half2 a[4] = {zero2, zero2, zero2, zero2};
#pragma unroll
        for (int j = 0; j < NJ; ++j) {
            a[0] = __hfma2(wr[j], b2h(d[j].x), a[0]);
            a[1] = __hfma2(wr[j], b2h(d[j].y), a[1]);
            a[2] = __hfma2(wr[j], b2h(d[j].z), a[2]);
            a[3] = __hfma2(wr[j], b2h(d[j].w), a[3]);
        }
#pragma unroll
        for (int m = 0; m < 4; ++m) {
            mx2[m] = h2max(mx2[m], a[m]);
            ct2[m] = b2h(pkadd(h2b(ct2[m]), pkfma_clamp(h2b(a[m]), C4b, ctermb)));
        }
#pragma unroll
        for (int j = 0; j < NJ; ++j) addr[j] += 1024;
    }
    const int rem = lout & 63;
    if (rem) {                                 // straddle chunk, lane-masked
        uint4 d[NJ];
#pragma unroll
        for (int j = 0; j < NJ; ++j) {
            if (j & 1) d[j] = *reinterpret_cast<const uint4*>(gxt + addr[j]);
            else       d[j] = *reinterpret_cast<const uint4*>(xsc + addr[j]);
        }
        __half2 a[4] = {zero2, zero2, zero2, zero2};
#pragma unroll
        for (int j = 0; j < NJ; ++j) {
            a[0] = __hfma2(wr[j], b2h(d[j].x), a[0]);
            a[1] = __hfma2(wr[j], b2h(d[j].y), a[1]);
            a[2] = __hfma2(wr[j], b2h(d[j].z), a[2]);
            a[3] = __hfma2(wr[j], b2h(d[j].w), a[3]);
        }
        const bool tm = lane < rem;
#pragma unroll
        for (int m = 0; m < 4; ++m) {
            a[m] = tm ? a[m] : nbig2;          // -65504*2^14 -> -inf -> clamp -> 0
            mx2[m] = h2max(mx2[m], a[m]);
            ct2[m] = b2h(pkadd(h2b(ct2[m]), pkfma_clamp(h2b(a[m]), C4b, ctermb)));
        }
    }

#pragma unroll
    for (int m = 0; m < 4; ++m) {
        um[m] = dpp_redmax(h2b(mx2[m]));
        uc[m] = dpp_redadd(h2b(ct2[m]));
    }
}

__global__ __launch_bounds__(256, 4)
void rocket_main(const unsigned short* __restrict__ xtg, const int* __restrict__ meta,
                 const float* __restrict__ bias, const int* __restrict__ l_out,
                 float* __restrict__ out, int K)
{
    __shared__ __align__(16) unsigned xs_u[WSLOT * 4];   // 25600 B fixed window

    const int kbase = (int)blockIdx.x * KPB;
    const int grp   = blockIdx.y;
    const int tid   = threadIdx.x;
    const int wave  = tid >> 6, lane = tid & 63;

    // ---- stage fixed window into LDS (zeros in fringes); conflict-free b128 ----
    float4* xs4 = reinterpret_cast<float4*>(xs_u);
    const float4* src = reinterpret_cast<const float4*>(xtg) + (size_t)grp * WSLOT + SBASE;
    const float4 z4 = make_float4(0.f, 0.f, 0.f, 0.f);
    for (int i = tid; i < WSLOT; i += 256) {
        const int s = i - SBASE;
        xs4[i] = ((unsigned)s < (unsigned)SEQ) ? src[s] : z4;
    }
    __syncthreads();

    const int k = kbase + wave;
    if (k >= K) return;

    // ---- per-wave k: meta row as one coalesced 128B load + readlane ----
    const int mrow  = meta[(size_t)k * MSTR + (lane & 31)];
    const int nj    = __builtin_amdgcn_readlane(mrow, 0);
    const int lout  = __builtin_amdgcn_readfirstlane(l_out[k]);
    const float biasf = __int_as_float(__builtin_amdgcn_readfirstlane(__float_as_int(bias[k])));
    const unsigned ctermb = h2b(__float2half2_rn(biasf * 16384.f));

    unsigned um[4], uc[4];
    const char* xsc = reinterpret_cast<const char*>(xs_u);
    const char* gxt = reinterpret_cast<const char*>(xtg) + (size_t)grp * WSLOT * 16;
    if (nj <= 7)      conv_wave<7 >(xsc, gxt, mrow, lout, lane, ctermb, um, uc);
    else if (nj <= 9) conv_wave<9 >(xsc, gxt, mrow, lout, lane, ctermb, um, uc);
    else              conv_wave<11>(xsc, gxt, mrow, lout, lane, ctermb, um, uc);

    // ---- lane 63 finalizes: 8 batches x {max, ppv} ----
    if (lane == 63) {
        const float loutf = (float)lout;
#pragma unroll
        for (int m = 0; m < 4; ++m) {
            const __half2 hm = b2h(um[m]);
            const __half2 hc = b2h(uc[m]);
            float* o0 = out + (size_t)(grp * NBB + 2 * m) * (2 * K) + 2 * k;
            o0[0] = __low2float(hm) + biasf;           // deferred bias
            o0[1] = __low2float(hc) / loutf;
            float* o1 = o0 + 2 * K;
            o1[0] = __high2float(hm) + biasf;
            o1[1] = __high2float(hc) / loutf;
        }
    }
}

// ======================= launch =======================
extern "C" void kernel_launch(void* const* d_in, const int* in_sizes, int n_in,
                              void* d_out, int out_size, void* d_ws, size_t ws_size,
                              hipStream_t stream)
{
    const float* x    = (const float*)d_in[0];
    const float* w    = (const float*)d_in[1];
    const float* bias = (const float*)d_in[2];
    const int*   idx  = (const int*)d_in[3];
    // d_in[4] = valid (unused: validity derived exactly from the idx ramp)
    const int*   lout = (const int*)d_in[5];
    float* out = (float*)d_out;

    const int K    = in_sizes[2];               // N_KERNELS
    const int maxL = in_sizes[3] / (K * KMAX);  // idx = [K][KMAX][maxL]

    // workspace: meta (K*32 ints, 128KB) | xtg (8 grps * 1600 slots * 16B = 200KB)
    int* meta = (int*)d_ws;
    size_t meta_bytes = ((size_t)K * MSTR * sizeof(int) + 255) & ~(size_t)255;
    unsigned short* xtg = (unsigned short*)((char*)d_ws + meta_bytes);

    prep_kernel<<<K + 32 + ZBLK, 256, 0, stream>>>(x, w, idx, meta, xtg, K, maxL);
    rocket_main<<<dim3((K + KPB - 1) / KPB, NGRP), 256, 0, stream>>>(xtg, meta, bias, lout, out, K);
}

// Round 15
// 34.483 us; speedup vs baseline: 1.1928x; 1.1928x over previous
//
#include <hip/hip_runtime.h>
#include <hip/hip_fp16.h>
#include <float.h>

constexpr int KMAX  = 11;    // KS_MAX
constexpr int SEQ   = 512;   // SEQ_LEN
constexpr int NB    = 64;    // BATCH
constexpr int NBB   = 8;     // batches per main block (8 groups)
constexpr int NGRP  = NB / NBB;
constexpr int KPB   = 4;     // kernels per block = 1 per wave
constexpr int MSTR  = 32;    // meta ints per k: [0]=nj [1..11]=c [12..22]=w2bits
constexpr int X0    = 64;    // fixed window: slot = s + 64
constexpr int WSLOT = 640;   // s in [-64, 576); guarded reads hit s in [-63, 574] only

__device__ __forceinline__ unsigned h2b(__half2 h) { unsigned u; __builtin_memcpy(&u, &h, 4); return u; }
__device__ __forceinline__ __half2  b2h(unsigned u) { __half2 h; __builtin_memcpy(&h, &u, 4); return h; }

// ROCm 7.2 has no __hmax2/__hmin2 — use VOP3P directly.
__device__ __forceinline__ unsigned pkmax(unsigned a, unsigned b) {
    unsigned d; asm("v_pk_max_f16 %0, %1, %2" : "=v"(d) : "v"(a), "v"(b)); return d;
}
__device__ __forceinline__ unsigned pkadd(unsigned a, unsigned b) { return h2b(__hadd2(b2h(a), b2h(b))); }
__device__ __forceinline__ __half2 h2max(__half2 a, __half2 b) { return b2h(pkmax(h2b(a), h2b(b))); }
// fused (a*b+c) clamped to [0,1] — the whole count update in one VOP3P
__device__ __forceinline__ unsigned pkfma_clamp(unsigned a, unsigned b, unsigned c) {
    unsigned d; asm("v_pk_fma_f16 %0, %1, %2, %3 clamp" : "=v"(d) : "v"(a), "v"(b), "v"(c)); return d;
}

template<int CTRL>
__device__ __forceinline__ unsigned dppmov(unsigned old, unsigned v) {
    return (unsigned)__builtin_amdgcn_update_dpp((int)old, (int)v, CTRL, 0xF, 0xF, false);
}
constexpr unsigned NEGINF2 = 0xFC00FC00u;   // -inf | -inf (f16 pair)

__device__ __forceinline__ unsigned dpp_redmax(unsigned x) {
    x = pkmax(x, dppmov<0xB1 >(NEGINF2, x));  // quad_perm xor1
    x = pkmax(x, dppmov<0x4E >(NEGINF2, x));  // quad_perm xor2
    x = pkmax(x, dppmov<0x141>(NEGINF2, x));  // row_half_mirror
    x = pkmax(x, dppmov<0x140>(NEGINF2, x));  // row_mirror
    x = pkmax(x, dppmov<0x142>(NEGINF2, x));  // row_bcast15
    x = pkmax(x, dppmov<0x143>(NEGINF2, x));  // row_bcast31
    return x;                                  // lane 63 valid
}
__device__ __forceinline__ unsigned dpp_redadd(unsigned x) {
    x = pkadd(x, dppmov<0xB1 >(0u, x));
    x = pkadd(x, dppmov<0x4E >(0u, x));
    x = pkadd(x, dppmov<0x141>(0u, x));
    x = pkadd(x, dppmov<0x140>(0u, x));
    x = pkadd(x, dppmov<0x142>(0u, x));
    x = pkadd(x, dppmov<0x143>(0u, x));
    return x;                                  // lane 63 valid
}

// ======================= prep kernel =======================
// blocks [0, K):    meta: c_kj via ONE stride-16 probe (+dense fallback), compaction.
// blocks [K, K+32): transpose+convert x (NB x SEQ f32) -> xt16[g][s][8] f16
__global__ __launch_bounds__(256)
void prep_kernel(const float* __restrict__ x, const float* __restrict__ w,
                 const int* __restrict__ idx, int* __restrict__ meta,
                 unsigned short* __restrict__ xt, int K, int maxL)
{
    const int tid = threadIdx.x;
    if ((int)blockIdx.x >= K) {
        const int j  = ((int)blockIdx.x - K) * 256 + tid;   // 0..8191
        const int b  = j >> 7, s4 = j & 127;
        const float4 v = reinterpret_cast<const float4*>(x)[b * (SEQ / 4) + s4];
        const int g = b >> 3, bl = b & 7;
        unsigned short* dst = xt + ((size_t)g * SEQ + s4 * 4) * NBB + bl;
        __half h;
        h = __float2half_rn(v.x); __builtin_memcpy(&dst[0 * NBB], &h, 2);
        h = __float2half_rn(v.y); __builtin_memcpy(&dst[1 * NBB], &h, 2);
        h = __float2half_rn(v.z); __builtin_memcpy(&dst[2 * NBB], &h, 2);
        h = __float2half_rn(v.w); __builtin_memcpy(&dst[3 * NBB], &h, 2);
        return;
    }

    // ---- meta: idx[k,j,t] = clip(t+c, 0, 511); interior value (0<v<511) => c = v-t.
    // Stride-16 probe t in {0,16,...,1008} clamped to maxL-1: the interior t-run
    // ((-c, 511-c) ∩ [0,maxL)) is >=509 wide or abuts the clamp point, so a probe
    // point always lands in it for realizable c in [-510, 510]. Fallback kept.
    __shared__ int c_sh[KMAX];
    const int k = blockIdx.x, wave = tid >> 6, lane = tid & 63;
    const int tprobe = min(lane * 16, maxL - 1);

    int vv[3] = {0, 0, 0};
#pragma unroll
    for (int i = 0; i < 3; ++i) {                // hoist: all probe loads in flight
        const int j = wave + i * 4;
        if (j < KMAX) vv[i] = idx[((size_t)k * KMAX + j) * (size_t)maxL + tprobe];
    }
#pragma unroll
    for (int i = 0; i < 3; ++i) {
        const int j = wave + i * 4;              // wave-uniform guard
        if (j < KMAX) {
            int c = 0;                           // fallback c=0 (in-window, w=0 -> 0)
            const bool interior = (vv[i] > 0) && (vv[i] < SEQ - 1);
            const unsigned long long mb = __ballot(interior);
            if (mb != 0ull) {
                const int fl = __builtin_ctzll(mb);
                c = __shfl(vv[i], fl) - min(fl * 16, maxL - 1);
            } else {
                const int* row = idx + ((size_t)k * KMAX + j) * (size_t)maxL;
                for (int base = 0; base < maxL; base += 64) {
                    const int t2 = base + lane;
                    const int v2 = (t2 < maxL) ? row[t2] : 0;
                    const bool in2 = (v2 > 0) && (v2 < SEQ - 1);
                    const unsigned long long mb2 = __ballot(in2);
                    if (mb2 != 0ull) {
                        const int fl2 = __builtin_ctzll(mb2);
                        c = __shfl(v2, fl2) - (base + fl2);
                        break;
                    }
                }
            }
            if (lane == 0) c_sh[j] = c;
        }
    }
    __syncthreads();

    if (tid == 0) {
        int* mk = meta + (size_t)k * MSTR;
        int n = 0;
        for (int j = 0; j < KMAX; ++j) {
            const float wj = w[(size_t)k * KMAX + j];
            if (wj != 0.0f) {
                mk[1 + n] = c_sh[j];
                __half hw = __float2half_rn(wj);
                unsigned short ub; __builtin_memcpy(&ub, &hw, 2);
                mk[12 + n] = (unsigned)ub | ((unsigned)ub << 16);
                ++n;
            }
        }
        // pads: c = 1<<20 makes the guard ALWAYS false -> tap fully skipped
        for (int jj = n; jj < KMAX; ++jj) { mk[1 + jj] = 1 << 20; mk[12 + jj] = 0; }
        mk[0] = n;
    }
}

// ======================= main kernel =======================
// grid (K/4, 8): block = (4 kernels, 8-batch group). 256 threads = 4 waves.
// FIXED 640-slot window (10.25 KB -> 8 blocks/CU = 32 waves): slot = s+64, zeros
// outside s in [0,512). One staging barrier, then each wave owns kernel k:
// per (tap, 64-t chunk) a wave-uniform SALU guard (tb+c+63 < 575) skips reads
// AND math for chunks whose tap window is entirely outside [0,512) — the skipped
// contribution is exactly 0, matching what the zero-fringe read produced. Guarded
// reads land in slot [1, 638] -> always in-window. DPP reductions on VALU pipe.
template<int NJ>
__device__ __forceinline__ void conv_wave(
    const char* __restrict__ xsc, int mrow, int lout, int lane, unsigned ctermb,
    unsigned (&um)[4], unsigned (&uc)[4])
{
    const __half2 zero2 = __float2half2_rn(0.f);
    const __half2 nbig2 = __float2half2_rn(-65504.f);
    const unsigned C4b  = 0x74007400u;   // f16 pair {2^14, 2^14}

    int addr[NJ], cs[NJ]; __half2 wr[NJ];
#pragma unroll
    for (int j = 0; j < NJ; ++j) {
        cs[j]   = __builtin_amdgcn_readlane(mrow, 1 + j);
        wr[j]   = b2h((unsigned)__builtin_amdgcn_readlane(mrow, 12 + j));
        addr[j] = (lane + cs[j] + X0) * 16;
    }
    __half2 mx2[4], ct2[4];
#pragma unroll
    for (int m = 0; m < 4; ++m) { mx2[m] = nbig2; ct2[m] = zero2; }

    const int nfull = lout >> 6;
    const int ng4   = nfull >> 2;

    for (int g = 0; g < ng4; ++g) {       // groups of 4 full chunks, immediate offsets
        const int gb = g * 256;
#pragma unroll
        for (int u = 0; u < 4; ++u) {
            const int tb = gb + u * 64;
            __half2 a[4] = {zero2, zero2, zero2, zero2};
#pragma unroll
            for (int j = 0; j < NJ; ++j) {
                if ((unsigned)(tb + cs[j] + 63) < 575u) {   // SALU skip: read+math
                    const uint4 d = *reinterpret_cast<const uint4*>(xsc + addr[j] + u * 1024);
                    a[0] = __hfma2(wr[j], b2h(d.x), a[0]);
                    a[1] = __hfma2(wr[j], b2h(d.y), a[1]);
                    a[2] = __hfma2(wr[j], b2h(d.z), a[2]);
                    a[3] = __hfma2(wr[j], b2h(d.w), a[3]);
                }
            }
#pragma unroll
            for (int m = 0; m < 4; ++m) {
                mx2[m] = h2max(mx2[m], a[m]);
                ct2[m] = b2h(pkadd(h2b(ct2[m]), pkfma_clamp(h2b(a[m]), C4b, ctermb)));
            }
        }
#pragma unroll
        for (int j = 0; j < NJ; ++j) addr[j] += 4096;
    }
    for (int u = 0; u < (nfull & 3); ++u) {   // leftover full chunks
        const int tb = ng4 * 256 + u * 64;
        __half2 a[4] = {zero2, zero2, zero2, zero2};
#pragma unroll
        for (int j = 0; j < NJ; ++j) {
            if ((unsigned)(tb + cs[j] + 63) < 575u) {
                const uint4 d = *reinterpret_cast<const uint4*>(xsc + addr[j]);
                a[0] = __hfma2(wr[j], b2h(d.x), a[0]);
                a[1] = __hfma2(wr[j], b2h(d.y), a[1]);
                a[2] = __hfma2(wr[j], b2h(d.z), a[2]);
                a[3] = __hfma2(wr[j], b2h(d.w), a[3]);
            }
        }
#pragma unroll
        for (int m = 0; m < 4; ++m) {
            mx2[m] = h2max(mx2[m], a[m]);
            ct2[m] = b2h(pkadd(h2b(ct2[m]), pkfma_clamp(h2b(a[m]), C4b, ctermb)));
        }
#pragma unroll
        for (int j = 0; j < NJ; ++j) addr[j] += 1024;
    }
    const int rem = lout & 63;
    if (rem) {                                 // straddle chunk, lane-masked
        const int tb = nfull * 64;
        __half2 a[4] = {zero2, zero2, zero2, zero2};
#pragma unroll
        for (int j = 0; j < NJ; ++j) {
            if ((unsigned)(tb + cs[j] + 63) < 575u) {
                const uint4 d = *reinterpret_cast<const uint4*>(xsc + addr[j]);
                a[0] = __hfma2(wr[j], b2h(d.x), a[0]);
                a[1] = __hfma2(wr[j], b2h(d.y), a[1]);
                a[2] = __hfma2(wr[j], b2h(d.z), a[2]);
                a[3] = __hfma2(wr[j], b2h(d.w), a[3]);
            }
        }
        const bool tm = lane < rem;
#pragma unroll
        for (int m = 0; m < 4; ++m) {
            a[m] = tm ? a[m] : nbig2;          // -65504*2^14 -> -inf -> clamp -> 0
            mx2[m] = h2max(mx2[m], a[m]);
            ct2[m] = b2h(pkadd(h2b(ct2[m]), pkfma_clamp(h2b(a[m]), C4b, ctermb)));
        }
    }

#pragma unroll
    for (int m = 0; m < 4; ++m) {
        um[m] = dpp_redmax(h2b(mx2[m]));
        uc[m] = dpp_redadd(h2b(ct2[m]));
    }
}

__global__ __launch_bounds__(256, 8)
void rocket_main(const unsigned short* __restrict__ xt, const int* __restrict__ meta,
                 const float* __restrict__ bias, const int* __restrict__ l_out,
                 float* __restrict__ out, int K)
{
    __shared__ __align__(16) unsigned xs_u[WSLOT * 4];   // 10240 B fixed window

    const int kbase = (int)blockIdx.x * KPB;
    const int grp   = blockIdx.y;
    const int tid   = threadIdx.x;
    const int wave  = tid >> 6, lane = tid & 63;

    // ---- stage: zero 128 fringe slots + copy 512 real slots (all b128) ----
    float4* xs4 = reinterpret_cast<float4*>(xs_u);
    if (tid < 2 * X0) {
        const int slot = (tid < X0) ? tid : tid + SEQ;   // [0,64) U [576,640)
        xs4[slot] = make_float4(0.f, 0.f, 0.f, 0.f);
    }
    const float4* src = reinterpret_cast<const float4*>(xt + (size_t)grp * SEQ * NBB);
    xs4[X0 + tid]       = src[tid];
    xs4[X0 + 256 + tid] = src[256 + tid];
    __syncthreads();

    const int k = kbase + wave;
    if (k >= K) return;

    // ---- per-wave k: meta row as one coalesced 128B load + readlane ----
    const int mrow  = meta[(size_t)k * MSTR + (lane & 31)];
    const int nj    = __builtin_amdgcn_readlane(mrow, 0);
    const int lout  = __builtin_amdgcn_readfirstlane(l_out[k]);
    const float biasf = __int_as_float(__builtin_amdgcn_readfirstlane(__float_as_int(bias[k])));
    const unsigned ctermb = h2b(__float2half2_rn(biasf * 16384.f));

    unsigned um[4], uc[4];
    const char* xsc = reinterpret_cast<const char*>(xs_u);
    if (nj <= 7)      conv_wave<7 >(xsc, mrow, lout, lane, ctermb, um, uc);
    else if (nj <= 9) conv_wave<9 >(xsc, mrow, lout, lane, ctermb, um, uc);
    else              conv_wave<11>(xsc, mrow, lout, lane, ctermb, um, uc);

    // ---- lane 63 finalizes: 8 batches x {max, ppv} ----
    if (lane == 63) {
        const float loutf = (float)lout;
#pragma unroll
        for (int m = 0; m < 4; ++m) {
            const __half2 hm = b2h(um[m]);
            const __half2 hc = b2h(uc[m]);
            float* o0 = out + (size_t)(grp * NBB + 2 * m) * (2 * K) + 2 * k;
            o0[0] = __low2float(hm) + biasf;           // deferred bias
            o0[1] = __low2float(hc) / loutf;
            float* o1 = o0 + 2 * K;
            o1[0] = __high2float(hm) + biasf;
            o1[1] = __high2float(hc) / loutf;
        }
    }
}

// ======================= launch =======================
extern "C" void kernel_launch(void* const* d_in, const int* in_sizes, int n_in,
                              void* d_out, int out_size, void* d_ws, size_t ws_size,
                              hipStream_t stream)
{
    const float* x    = (const float*)d_in[0];
    const float* w    = (const float*)d_in[1];
    const float* bias = (const float*)d_in[2];
    const int*   idx  = (const int*)d_in[3];
    // d_in[4] = valid (unused: validity derived exactly from the idx ramp)
    const int*   lout = (const int*)d_in[5];
    float* out = (float*)d_out;

    const int K    = in_sizes[2];               // N_KERNELS
    const int maxL = in_sizes[3] / (K * KMAX);  // idx = [K][KMAX][maxL]

    // workspace: meta (K*32 ints) | xt16 (NB*SEQ f16), 256B-aligned split
    int* meta = (int*)d_ws;
    size_t meta_bytes = ((size_t)K * MSTR * sizeof(int) + 255) & ~(size_t)255;
    unsigned short* xt = (unsigned short*)((char*)d_ws + meta_bytes);

    prep_kernel<<<K + 32, 256, 0, stream>>>(x, w, idx, meta, xt, K, maxL);
    rocket_main<<<dim3((K + KPB - 1) / KPB, NGRP), 256, 0, stream>>>(xt, meta, bias, lout, out, K);
}